// Round 5
// baseline (243.664 us; speedup 1.0000x reference)
//
#include <hip/hip_runtime.h>
#include <math.h>

#define DEV __device__ __forceinline__

// Packed fp32 pair: .x = row A, .y = row B -> v_pk_fma_f32 (2 rows/inst).
typedef float f2 __attribute__((ext_vector_type(2)));

DEV f2 splat(float s) { f2 r; r.x = s; r.y = s; return r; }

// Layer sizes (w,b interleaved): fc1..fc14 of DIMS.
// R4 theory: weights pre-splatted to {w,w} f2 in d_ws. A uniform f2 load is
// an s_load_dwordx2 -> SGPR pair, which VOP3P v_pk_fma_f32 consumes directly.
// This deletes the per-weight v_mov (SGPR->VGPR splat materialization) that
// R3's inst-count model identified as ~1300 of ~3060 VALU insts/pair.

// ---- setup kernel: splat fp32 weights/biases into f2 in workspace ----
struct SrcPtrs { const float* p[28]; };

__global__ void __launch_bounds__(256)
splat_weights(SrcPtrs ps, f2* __restrict__ ws) {
    // lengths of w1,b1,w2,b2,...,w14,b14
    const int LEN[28] = {144,12, 132,11, 110,10, 90,9, 72,8, 56,7, 42,6,
                         42,7, 56,8, 72,9, 90,10, 110,11, 132,12, 24,2};
    int tid    = threadIdx.x + blockIdx.x * blockDim.x;
    int stride = blockDim.x * gridDim.x;
    int off = 0;
    for (int s = 0; s < 28; ++s) {
        const float* src = ps.p[s];
        for (int i = tid; i < LEN[s]; i += stride) {
            float v = src[i];
            f2 d; d.x = v; d.y = v;
            ws[off + i] = d;
        }
        off += LEN[s];
    }
}

// k-outer linear layer on pre-splatted f2 weights.
template <int DIN, int DOUT>
DEV void lin2(const f2* __restrict__ w, const f2* __restrict__ b,
              const f2* in, f2* out) {
#pragma unroll
    for (int o = 0; o < DOUT; ++o) out[o] = b[o];
#pragma unroll
    for (int k = 0; k < DIN; ++k) {
        f2 xk = in[k];
#pragma unroll
        for (int o = 0; o < DOUT; ++o)
            out[o] = __builtin_elementwise_fma(xk, w[o * DIN + k], out[o]);
    }
}

// Accumulator starts at bias + skip (fused decoder skip-add).
template <int DIN, int DOUT>
DEV void lin2_skip(const f2* __restrict__ w, const f2* __restrict__ b,
                   const f2* in, const f2* skip, f2* out) {
#pragma unroll
    for (int o = 0; o < DOUT; ++o) out[o] = b[o] + skip[o];
#pragma unroll
    for (int k = 0; k < DIN; ++k) {
        f2 xk = in[k];
#pragma unroll
        for (int o = 0; o < DOUT; ++o)
            out[o] = __builtin_elementwise_fma(xk, w[o * DIN + k], out[o]);
    }
}

template <int N>
DEV void relu_ip(f2* v) {
#pragma unroll
    for (int k = 0; k < N; ++k) v[k] = __builtin_elementwise_max(v[k], splat(0.0f));
}

__global__ void __launch_bounds__(256, 2)
csnet14_kernel(const float* __restrict__ x, const f2* __restrict__ ws,
               float* __restrict__ out, int nt) {
    // Pre-splatted layout in ws (f2 elements): w1 b1 w2 b2 ... w14 b14
    const f2* w1  = ws;         const f2* b1  = w1  + 144;
    const f2* w2  = b1  + 12;   const f2* b2  = w2  + 132;
    const f2* w3  = b2  + 11;   const f2* b3  = w3  + 110;
    const f2* w4  = b3  + 10;   const f2* b4  = w4  + 90;
    const f2* w5  = b4  + 9;    const f2* b5  = w5  + 72;
    const f2* w6  = b5  + 8;    const f2* b6  = w6  + 56;
    const f2* w7  = b6  + 7;    const f2* b7  = w7  + 42;
    const f2* w8  = b7  + 6;    const f2* b8  = w8  + 42;
    const f2* w9  = b8  + 7;    const f2* b9  = w9  + 56;
    const f2* w10 = b9  + 8;    const f2* b10 = w10 + 72;
    const f2* w11 = b10 + 9;    const f2* b11 = w11 + 90;
    const f2* w12 = b11 + 10;   const f2* b12 = w12 + 110;
    const f2* w13 = b12 + 11;   const f2* b13 = w13 + 132;
    const f2* w14 = b13 + 12;   const f2* b14 = w14 + 24;

    int t = blockIdx.x * blockDim.x + threadIdx.x;
    if (t >= nt) return;  // nt = n/2 row-pairs

    // Two adjacent rows: 24 contiguous floats = 6x float4 (96 B).
    const float4* xr = reinterpret_cast<const float4*>(x + (size_t)t * 24);
    float4 a0 = xr[0], a1 = xr[1], a2 = xr[2];
    float4 a3 = xr[3], a4 = xr[4], a5 = xr[5];
    float r0[12] = {a0.x, a0.y, a0.z, a0.w, a1.x, a1.y, a1.z, a1.w,
                    a2.x, a2.y, a2.z, a2.w};
    float r1[12] = {a3.x, a3.y, a3.z, a3.w, a4.x, a4.y, a4.z, a4.w,
                    a5.x, a5.y, a5.z, a5.w};
    f2 h0[12];
#pragma unroll
    for (int k = 0; k < 12; ++k) { h0[k].x = r0[k]; h0[k].y = r1[k]; }

    // Encoder: fc1..fc6, save post-ReLU identities.
    f2 id1[12]; lin2<12, 12>(w1, b1, h0,  id1); relu_ip<12>(id1);
    f2 id2[11]; lin2<12, 11>(w2, b2, id1, id2); relu_ip<11>(id2);
    f2 id3[10]; lin2<11, 10>(w3, b3, id2, id3); relu_ip<10>(id3);
    f2 id4[9];  lin2<10,  9>(w4, b4, id3, id4); relu_ip<9>(id4);
    f2 id5[8];  lin2< 9,  8>(w5, b5, id4, id5); relu_ip<8>(id5);
    f2 id6[7];  lin2< 8,  7>(w6, b6, id5, id6); relu_ip<7>(id6);

    // Bottleneck fc7.
    f2 t7[6];   lin2< 7,  6>(w7, b7, id6, t7);  relu_ip<6>(t7);

    // Decoder: fc8..fc13, skip fused into accumulator init.
    f2 t8[7];   lin2_skip< 6,  7>(w8,  b8,  t7,  id6, t8);  relu_ip<7>(t8);
    f2 t9[8];   lin2_skip< 7,  8>(w9,  b9,  t8,  id5, t9);  relu_ip<8>(t9);
    f2 t10[9];  lin2_skip< 8,  9>(w10, b10, t9,  id4, t10); relu_ip<9>(t10);
    f2 t11[10]; lin2_skip< 9, 10>(w11, b11, t10, id3, t11); relu_ip<10>(t11);
    f2 t12[11]; lin2_skip<10, 11>(w12, b12, t11, id2, t12); relu_ip<11>(t12);
    f2 t13[12]; lin2_skip<11, 12>(w13, b13, t12, id1, t13); relu_ip<12>(t13);

    // fc14 (12 -> 2) + softmax, both rows.
    f2 l[2];    lin2<12,  2>(w14, b14, t13, l);
    f2 m  = __builtin_elementwise_max(l[0], l[1]);
    f2 d0 = l[0] - m;
    f2 d1 = l[1] - m;
    float e0a = __expf(d0.x), e0b = __expf(d0.y);
    float e1a = __expf(d1.x), e1b = __expf(d1.y);
    float inva = __builtin_amdgcn_rcpf(e0a + e1a);
    float invb = __builtin_amdgcn_rcpf(e0b + e1b);

    float4 o;  // rows 2t, 2t+1 -> out[4t..4t+3], coalesced 16 B/lane
    o.x = e0a * inva;
    o.y = e1a * inva;
    o.z = e0b * invb;
    o.w = e1b * invb;
    reinterpret_cast<float4*>(out)[t] = o;
}

extern "C" void kernel_launch(void* const* d_in, const int* in_sizes, int n_in,
                              void* d_out, int out_size, void* d_ws, size_t ws_size,
                              hipStream_t stream) {
    const float* x = (const float*)d_in[0];
    float* out = (float*)d_out;
    f2* ws = (f2*)d_ws;  // needs 1294+122 = 1416 f2 = 11,328 B

    SrcPtrs ps;
    for (int i = 0; i < 28; ++i) ps.p[i] = (const float*)d_in[1 + i];

    // Setup: splat weights/biases to {v,v} pairs in workspace (every call;
    // d_ws is re-poisoned before each timed launch).
    splat_weights<<<4, 256, 0, stream>>>(ps, ws);

    const int n  = in_sizes[0] / 12;  // 2,000,000 rows (even)
    const int nt = n / 2;             // row-pairs
    dim3 block(256);
    dim3 grid((nt + 255) / 256);
    csnet14_kernel<<<grid, block, 0, stream>>>(x, ws, out, nt);
}